// Round 1
// baseline (418.816 us; speedup 1.0000x reference)
//
#include <hip/hip_runtime.h>

// Problem constants (fixed shapes from the reference):
// B=16, N=32 targets/batch (512 total), NS=3 scales, NA=3 anchors, NC=80.
// Grids: 64, 32, 16. Cells per scale = 16*3*g*g.
constexpr int S0 = 16 * 3 * 64 * 64;  // 196608
constexpr int S1 = 16 * 3 * 32 * 32;  // 49152
constexpr int S2 = 16 * 3 * 16 * 16;  // 12288
constexpr int TOT = S0 + S1 + S2;     // 258048
constexpr int BITWORDS = TOT / 32;    // 8064 words = 32256 B LDS bitset

__device__ __forceinline__ float softplusf(float x) {
    // jax.nn.softplus = logaddexp(x,0) = max(x,0) + log1p(exp(-|x|))
    return fmaxf(x, 0.0f) + log1pf(expf(-fabsf(x)));
}

// K1: one block, 512 threads (one per target). Computes, per scale s:
//   cnt_s   = sum mf            -> ws[1..3]
//   box_s   = sum (1-iou)*mf    -> ws[4..6]
//   cls_s   = sum cls_bce*mf    -> ws[7..9]
//   obj corr= sum over UNIQUE marked cells of (-p4)/M_s  -> ws[0] (init)
// Dedupe of the t_obj scatter-max via an LDS bitset over all 258048 cells.
__global__ __launch_bounds__(512) void yolo_targets_kernel(
    const float* __restrict__ inf0, const float* __restrict__ inf1,
    const float* __restrict__ inf2, const float* __restrict__ anchors,
    const float* __restrict__ strides, const float* __restrict__ targets,
    float* __restrict__ ws)
{
    __shared__ unsigned int bits[BITWORDS];
    __shared__ float s_cnt[3], s_box[3], s_cls[3], s_obj;
    const int tid = threadIdx.x;
    for (int i = tid; i < BITWORDS; i += 512) bits[i] = 0u;
    if (tid < 3) { s_cnt[tid] = 0.f; s_box[tid] = 0.f; s_cls[tid] = 0.f; }
    if (tid == 0) s_obj = 0.f;
    __syncthreads();

    const float* infs[3] = {inf0, inf1, inf2};
    const int   gs[3]       = {64, 32, 16};
    const int   cellbase[3] = {0, S0, S0 + S1};
    const float invM[3]     = {1.0f/(float)S0, 1.0f/(float)S1, 1.0f/(float)S2};

    const int t = tid;            // 512 targets exactly
    const int b = t >> 5;         // t / 32
    const float x = targets[t*5+0];
    const float y = targets[t*5+1];
    const float w = targets[t*5+2];
    const float h = targets[t*5+3];
    const int cls = (int)targets[t*5+4];

    #pragma unroll
    for (int s = 0; s < 3; ++s) {
        const float st = strides[s];
        const float tbx = x / st, tby = y / st, tbw = w / st, tbh = h / st;
        const float cif = floorf(tbx), cjf = floorf(tby);
        const int ci = (int)cif, cj = (int)cjf;
        const float fx = tbx - cif, fy = tby - cjf;
        const float tx0 = fx - tbw*0.5f, ty0 = fy - tbh*0.5f;
        const float tx1 = fx + tbw*0.5f, ty1 = fy + tbh*0.5f;
        const float tarea = tbw * tbh;
        const int g = gs[s];
        #pragma unroll
        for (int a = 0; a < 3; ++a) {
            const float aw = anchors[(s*3+a)*2+0] / st;
            const float ah = anchors[(s*3+a)*2+1] / st;
            const float ax0 = 0.5f - aw*0.5f, ay0 = 0.5f - ah*0.5f;
            const float ax1 = 0.5f + aw*0.5f, ay1 = 0.5f + ah*0.5f;
            // jaccard(tb_rect, anchor_rect) with (x0<x1)&(y0<y1) gating
            const float ix0 = fmaxf(tx0, ax0), iy0 = fmaxf(ty0, ay0);
            const float ix1 = fminf(tx1, ax1), iy1 = fminf(ty1, ay1);
            float inter = (ix1-ix0)*(iy1-iy0);
            inter = (ix0 < ix1 && iy0 < iy1) ? inter : 0.0f;
            const float uni = tarea + aw*ah - inter;
            const float iou = inter / uni;
            if (iou > 0.5f) {  // mf = 1
                atomicAdd(&s_cnt[s], 1.0f);
                const int cellflat = ((b*3 + a)*g + cj)*g + ci;
                const float* pred = infs[s] + (long)cellflat * 85;
                // box term: iou(pred_box, target_box)
                const float px = 1.0f / (1.0f + expf(-pred[0]));
                const float py = 1.0f / (1.0f + expf(-pred[1]));
                const float pw = fminf(expf(pred[2]), 1000.0f) * aw;
                const float ph = fminf(expf(pred[3]), 1000.0f) * ah;
                const float bx0 = px - pw*0.5f, by0 = py - ph*0.5f;
                const float bx1 = px + pw*0.5f, by1 = py + ph*0.5f;
                const float jx0 = fmaxf(bx0, tx0), jy0 = fmaxf(by0, ty0);
                const float jx1 = fminf(bx1, tx1), jy1 = fminf(by1, ty1);
                float inter2 = (jx1-jx0)*(jy1-jy0);
                inter2 = (jx0 < jx1 && jy0 < jy1) ? inter2 : 0.0f;
                const float uni2 = pw*ph + tarea - inter2;
                atomicAdd(&s_box[s], 1.0f - inter2 / uni2);
                // cls term: sum_c bce(pred[5+c], onehot) = sum softplus - pred[5+cls]
                float csum = 0.0f;
                #pragma unroll 4
                for (int c = 0; c < 80; ++c) csum += softplusf(pred[5+c]);
                csum -= pred[5 + cls];
                atomicAdd(&s_cls[s], csum);
                // t_obj dedupe: correction -p4 per UNIQUE cell
                const int cell = cellbase[s] + cellflat;
                const unsigned int wd = (unsigned int)cell >> 5;
                const unsigned int mk = 1u << (cell & 31);
                const unsigned int old = atomicOr(&bits[wd], mk);
                if (!(old & mk)) {
                    atomicAdd(&s_obj, -pred[4] * invM[s]);
                }
            }
        }
    }
    __syncthreads();
    if (tid == 0) {
        ws[0] = s_obj;   // initializes the obj accumulator (K2 atomicAdds onto it)
        ws[1] = s_cnt[0]; ws[2] = s_cnt[1]; ws[3] = s_cnt[2];
        ws[4] = s_box[0]; ws[5] = s_box[1]; ws[6] = s_box[2];
        ws[7] = s_cls[0]; ws[8] = s_cls[1]; ws[9] = s_cls[2];
    }
}

// K2: baseline obj term: sum over ALL cells of softplus(inf[...,4]) / M_s.
// Grid is exactly TOT/256 = 1008 blocks; block boundaries are scale-pure
// (768 / 192 / 48 blocks).
__global__ __launch_bounds__(256) void yolo_obj_kernel(
    const float* __restrict__ inf0, const float* __restrict__ inf1,
    const float* __restrict__ inf2, float* __restrict__ ws)
{
    const int idx = blockIdx.x * 256 + threadIdx.x;
    const float* inf; int local; float w;
    if (idx < S0)           { inf = inf0; local = idx;             w = 1.0f/(float)S0; }
    else if (idx < S0 + S1) { inf = inf1; local = idx - S0;        w = 1.0f/(float)S1; }
    else                    { inf = inf2; local = idx - (S0 + S1); w = 1.0f/(float)S2; }
    const float p = inf[(long)local * 85 + 4];
    float v = softplusf(p) * w;
    #pragma unroll
    for (int off = 32; off > 0; off >>= 1) v += __shfl_down(v, off, 64);
    __shared__ float wsum[4];
    const int lane = threadIdx.x & 63, wid = threadIdx.x >> 6;
    if (lane == 0) wsum[wid] = v;
    __syncthreads();
    if (threadIdx.x == 0) atomicAdd(&ws[0], wsum[0] + wsum[1] + wsum[2] + wsum[3]);
}

// K3: combine into the scalar loss.
__global__ void yolo_finalize_kernel(const float* __restrict__ ws,
                                     float* __restrict__ out)
{
    const float obj = ws[0];
    float box = 0.0f, cls = 0.0f;
    #pragma unroll
    for (int s = 0; s < 3; ++s) {
        const float cnt = fmaxf(ws[1 + s], 1.0f);
        box += ws[4 + s] / cnt;
        cls += ws[7 + s] / (cnt * 80.0f);
    }
    out[0] = 3.54f * box + 64.3f * obj + 37.4f * cls;
}

extern "C" void kernel_launch(void* const* d_in, const int* in_sizes, int n_in,
                              void* d_out, int out_size, void* d_ws, size_t ws_size,
                              hipStream_t stream) {
    const float* inf0    = (const float*)d_in[0];
    const float* inf1    = (const float*)d_in[1];
    const float* inf2    = (const float*)d_in[2];
    const float* anchors = (const float*)d_in[3];
    const float* strides = (const float*)d_in[4];
    const float* targets = (const float*)d_in[5];
    float* ws  = (float*)d_ws;
    float* out = (float*)d_out;

    yolo_targets_kernel<<<1, 512, 0, stream>>>(inf0, inf1, inf2, anchors,
                                               strides, targets, ws);
    yolo_obj_kernel<<<TOT / 256, 256, 0, stream>>>(inf0, inf1, inf2, ws);
    yolo_finalize_kernel<<<1, 1, 0, stream>>>(ws, out);
}

// Round 2
// 145.842 us; speedup vs baseline: 2.8717x; 2.8717x over previous
//
#include <hip/hip_runtime.h>

// Shapes: B=16, N=32 (512 targets), NS=3 scales, NA=3 anchors, NC=80.
// Grids 64/32/16. Cells per scale = 16*3*g*g.
constexpr int S0 = 16 * 3 * 64 * 64;  // 196608
constexpr int S1 = 16 * 3 * 32 * 32;  // 49152
constexpr int S2 = 16 * 3 * 16 * 16;  // 12288
constexpr int TOT = S0 + S1 + S2;     // 258048
constexpr int BITWORDS = TOT / 32;    // 8064 u32 words (32256 B)
constexpr int WS_ACC   = 16;          // ws[0..9] accumulators, bitset after 16 words
constexpr int WS_WORDS = WS_ACC + BITWORDS;

constexpr int TWAVES  = 512 * 9;          // 4608 waves, one per (t,s,a)
constexpr int TBLOCKS = TWAVES / 4;       // 1152 blocks of 256 (4 waves)
constexpr int OBLOCKS = TOT / 256;        // 1008 blocks for the dense obj term

__device__ __forceinline__ float softplusf(float x) {
    // softplus(x) = max(x,0) + log1p(exp(-|x|)); fast intrinsics are plenty
    // accurate for the 5.06 abs threshold.
    return fmaxf(x, 0.0f) + __logf(1.0f + __expf(-fabsf(x)));
}

// K0: zero the accumulators + global dedupe bitset (ws is poisoned 0xAA).
__global__ __launch_bounds__(256) void yolo_zero_kernel(unsigned int* __restrict__ w) {
    const int i = blockIdx.x * 256 + threadIdx.x;
    if (i < WS_WORDS) w[i] = 0u;
}

// K1 (fused): blocks [0, TBLOCKS) do per-target work, one WAVE per (t,s,a);
// blocks [TBLOCKS, TBLOCKS+OBLOCKS) do the dense obj baseline
// sum softplus(inf[...,4])/M_s over all cells.
__global__ __launch_bounds__(256) void yolo_main_kernel(
    const float* __restrict__ inf0, const float* __restrict__ inf1,
    const float* __restrict__ inf2, const float* __restrict__ anchors,
    const float* __restrict__ strides, const float* __restrict__ targets,
    float* __restrict__ ws)
{
    if (blockIdx.x < TBLOCKS) {
        // ---------------- target path: one wave per (t,s,a) ----------------
        const int wave = blockIdx.x * 4 + (threadIdx.x >> 6);
        const int lane = threadIdx.x & 63;
        const int t  = wave / 9;
        const int sa = wave - 9 * t;
        const int s  = sa / 3;
        const int a  = sa - 3 * s;
        const int b  = t >> 5;  // t / 32

        const float x = targets[t*5+0];
        const float y = targets[t*5+1];
        const float w = targets[t*5+2];
        const float h = targets[t*5+3];
        const int cls = (int)targets[t*5+4];

        const float st  = strides[s];
        const float tbx = x / st, tby = y / st, tbw = w / st, tbh = h / st;
        const float cif = floorf(tbx), cjf = floorf(tby);
        const int ci = (int)cif, cj = (int)cjf;
        const float fx = tbx - cif, fy = tby - cjf;
        const float tx0 = fx - tbw*0.5f, ty0 = fy - tbh*0.5f;
        const float tx1 = fx + tbw*0.5f, ty1 = fy + tbh*0.5f;
        const float tarea = tbw * tbh;

        const float aw = anchors[(s*3+a)*2+0] / st;
        const float ah = anchors[(s*3+a)*2+1] / st;
        const float ax0 = 0.5f - aw*0.5f, ay0 = 0.5f - ah*0.5f;
        const float ax1 = 0.5f + aw*0.5f, ay1 = 0.5f + ah*0.5f;
        const float ix0 = fmaxf(tx0, ax0), iy0 = fmaxf(ty0, ay0);
        const float ix1 = fminf(tx1, ax1), iy1 = fminf(ty1, ay1);
        float inter = (ix1-ix0)*(iy1-iy0);
        inter = (ix0 < ix1 && iy0 < iy1) ? inter : 0.0f;
        const float iou = inter / (tarea + aw*ah - inter);

        if (iou > 0.5f) {  // wave-uniform: every lane computed the same test
            const int g = (s == 0) ? 64 : (s == 1) ? 32 : 16;
            const float* inf = (s == 0) ? inf0 : (s == 1) ? inf1 : inf2;
            const float invM = (s == 0) ? 1.0f/(float)S0
                             : (s == 1) ? 1.0f/(float)S1 : 1.0f/(float)S2;
            const int cellbase = (s == 0) ? 0 : (s == 1) ? S0 : S0 + S1;

            const int cellflat = ((b*3 + a)*g + cj)*g + ci;
            const float* pred = inf + (long)cellflat * 85;

            // box term (redundant across lanes; broadcast loads)
            const float p0 = pred[0], p1 = pred[1], p2 = pred[2],
                        p3 = pred[3], p4 = pred[4];
            const float px = 1.0f / (1.0f + __expf(-p0));
            const float py = 1.0f / (1.0f + __expf(-p1));
            const float pw = fminf(__expf(p2), 1000.0f) * aw;
            const float ph = fminf(__expf(p3), 1000.0f) * ah;
            const float bx0 = px - pw*0.5f, by0 = py - ph*0.5f;
            const float bx1 = px + pw*0.5f, by1 = py + ph*0.5f;
            const float jx0 = fmaxf(bx0, tx0), jy0 = fmaxf(by0, ty0);
            const float jx1 = fminf(bx1, tx1), jy1 = fminf(by1, ty1);
            float inter2 = (jx1-jx0)*(jy1-jy0);
            inter2 = (jx0 < jx1 && jy0 < jy1) ? inter2 : 0.0f;
            const float iou2 = inter2 / (pw*ph + tarea - inter2);

            // cls term: lanes split the 80 classes (lane, lane+64)
            float v = softplusf(pred[5 + lane]);
            if (lane == cls) v -= pred[5 + cls];
            if (lane < 16) {
                const int c2 = 64 + lane;
                v += softplusf(pred[5 + c2]);
                if (c2 == cls) v -= pred[5 + c2];
            }
            #pragma unroll
            for (int off = 32; off > 0; off >>= 1) v += __shfl_down(v, off, 64);

            if (lane == 0) {
                atomicAdd(&ws[1 + s], 1.0f);          // cnt
                atomicAdd(&ws[4 + s], 1.0f - iou2);   // box
                atomicAdd(&ws[7 + s], v);             // cls
                // t_obj dedupe: -p4 per UNIQUE marked cell
                unsigned int* bitset = (unsigned int*)ws + WS_ACC;
                const int cell = cellbase + cellflat;
                const unsigned int wd = (unsigned int)cell >> 5;
                const unsigned int mk = 1u << (cell & 31);
                const unsigned int old = atomicOr(&bitset[wd], mk);
                if (!(old & mk)) atomicAdd(&ws[0], -p4 * invM);
            }
        }
    } else {
        // ---------------- dense obj baseline path ----------------
        const int idx = (blockIdx.x - TBLOCKS) * 256 + threadIdx.x;
        const float* inf; int local; float w;
        if (idx < S0)           { inf = inf0; local = idx;             w = 1.0f/(float)S0; }
        else if (idx < S0 + S1) { inf = inf1; local = idx - S0;        w = 1.0f/(float)S1; }
        else                    { inf = inf2; local = idx - (S0 + S1); w = 1.0f/(float)S2; }
        float v = softplusf(inf[(long)local * 85 + 4]) * w;
        #pragma unroll
        for (int off = 32; off > 0; off >>= 1) v += __shfl_down(v, off, 64);
        __shared__ float wsum[4];
        const int lane = threadIdx.x & 63, wid = threadIdx.x >> 6;
        if (lane == 0) wsum[wid] = v;
        __syncthreads();
        if (threadIdx.x == 0)
            atomicAdd(&ws[0], wsum[0] + wsum[1] + wsum[2] + wsum[3]);
    }
}

// K2: combine into the scalar loss.
__global__ void yolo_finalize_kernel(const float* __restrict__ ws,
                                     float* __restrict__ out)
{
    const float obj = ws[0];
    float box = 0.0f, cls = 0.0f;
    #pragma unroll
    for (int s = 0; s < 3; ++s) {
        const float cnt = fmaxf(ws[1 + s], 1.0f);
        box += ws[4 + s] / cnt;
        cls += ws[7 + s] / (cnt * 80.0f);
    }
    out[0] = 3.54f * box + 64.3f * obj + 37.4f * cls;
}

extern "C" void kernel_launch(void* const* d_in, const int* in_sizes, int n_in,
                              void* d_out, int out_size, void* d_ws, size_t ws_size,
                              hipStream_t stream) {
    const float* inf0    = (const float*)d_in[0];
    const float* inf1    = (const float*)d_in[1];
    const float* inf2    = (const float*)d_in[2];
    const float* anchors = (const float*)d_in[3];
    const float* strides = (const float*)d_in[4];
    const float* targets = (const float*)d_in[5];
    float* ws  = (float*)d_ws;
    float* out = (float*)d_out;

    yolo_zero_kernel<<<(WS_WORDS + 255) / 256, 256, 0, stream>>>((unsigned int*)ws);
    yolo_main_kernel<<<TBLOCKS + OBLOCKS, 256, 0, stream>>>(
        inf0, inf1, inf2, anchors, strides, targets, ws);
    yolo_finalize_kernel<<<1, 1, 0, stream>>>(ws, out);
}

// Round 3
// 113.848 us; speedup vs baseline: 3.6787x; 1.2810x over previous
//
#include <hip/hip_runtime.h>

// Shapes: B=16, N=32 (512 targets), NS=3 scales, NA=3 anchors, NC=80.
// Grids 64/32/16. Cells per scale = 16*3*g*g.
constexpr int S0 = 16 * 3 * 64 * 64;  // 196608
constexpr int S1 = 16 * 3 * 32 * 32;  // 49152
constexpr int S2 = 16 * 3 * 16 * 16;  // 12288
constexpr int TOT = S0 + S1 + S2;     // 258048

constexpr int TWAVES  = 512 * 9;      // one wave per (t,s,a)
constexpr int TBLOCKS = TWAVES / 4;   // 1152 blocks of 256 (4 waves)
constexpr int OBLOCKS = TOT / 256;    // 1008 dense obj blocks

// ws layout (floats): [0, TBLOCKS*10)            target-block partial rows
//                     [WS_OBJ, WS_OBJ + OBLOCKS)  dense obj partials
constexpr int WS_OBJ = TBLOCKS * 10;  // 11520

__device__ __forceinline__ float softplusf(float x) {
    return fmaxf(x, 0.0f) + __logf(1.0f + __expf(-fabsf(x)));
}

// Anchor-IoU hit test. MUST be the single definition used by both the wave's
// own test and the earlier-target dedupe test so results are bit-exact equal.
__device__ __forceinline__ bool anchor_hit(
    float x, float y, float w, float h, float st, float aw, float ah,
    int& ci, int& cj, float& fx, float& fy, float& tbw, float& tbh)
{
    const float tbx = x / st, tby = y / st;
    tbw = w / st; tbh = h / st;
    const float cif = floorf(tbx), cjf = floorf(tby);
    ci = (int)cif; cj = (int)cjf;
    fx = tbx - cif; fy = tby - cjf;
    const float tx0 = fx - tbw*0.5f, ty0 = fy - tbh*0.5f;
    const float tx1 = fx + tbw*0.5f, ty1 = fy + tbh*0.5f;
    const float ax0 = 0.5f - aw*0.5f, ay0 = 0.5f - ah*0.5f;
    const float ax1 = 0.5f + aw*0.5f, ay1 = 0.5f + ah*0.5f;
    const float ix0 = fmaxf(tx0, ax0), iy0 = fmaxf(ty0, ay0);
    const float ix1 = fminf(tx1, ax1), iy1 = fminf(ty1, ay1);
    float inter = (ix1-ix0)*(iy1-iy0);
    inter = (ix0 < ix1 && iy0 < iy1) ? inter : 0.0f;
    const float iou = inter / (tbw*tbh + aw*ah - inter);
    return iou > 0.5f;
}

// K1 (fused): blocks [0, TBLOCKS) -> per-target work, one WAVE per (t,s,a);
// blocks [TBLOCKS, TBLOCKS+OBLOCKS) -> dense obj baseline. NO global atomics:
// every block writes its partial to a private ws slot.
__global__ __launch_bounds__(256) void yolo_main_kernel(
    const float* __restrict__ inf0, const float* __restrict__ inf1,
    const float* __restrict__ inf2, const float* __restrict__ anchors,
    const float* __restrict__ strides, const float* __restrict__ targets,
    float* __restrict__ ws)
{
    if (blockIdx.x < TBLOCKS) {
        // ---------------- target path: one wave per (t,s,a) ----------------
        __shared__ float s_part[10];
        if (threadIdx.x < 10) s_part[threadIdx.x] = 0.0f;
        __syncthreads();

        const int wave = blockIdx.x * 4 + (threadIdx.x >> 6);
        const int lane = threadIdx.x & 63;
        const int t  = wave / 9;
        const int sa = wave - 9 * t;
        const int s  = sa / 3;
        const int a  = sa - 3 * s;
        const int b  = t >> 5;

        const float x = targets[t*5+0];
        const float y = targets[t*5+1];
        const float w = targets[t*5+2];
        const float h = targets[t*5+3];
        const int cls = (int)targets[t*5+4];

        const float st = strides[s];
        const float aw = anchors[(s*3+a)*2+0] / st;
        const float ah = anchors[(s*3+a)*2+1] / st;

        int ci, cj; float fx, fy, tbw, tbh;
        const bool hit = anchor_hit(x, y, w, h, st, aw, ah,
                                    ci, cj, fx, fy, tbw, tbh);
        if (hit) {  // wave-uniform
            const int g = (s == 0) ? 64 : (s == 1) ? 32 : 16;
            const float* inf = (s == 0) ? inf0 : (s == 1) ? inf1 : inf2;
            const float invM = (s == 0) ? 1.0f/(float)S0
                             : (s == 1) ? 1.0f/(float)S1 : 1.0f/(float)S2;

            const int cellflat = ((b*3 + a)*g + cj)*g + ci;
            const float* pred = inf + (long)cellflat * 85;

            // box term (redundant across lanes; broadcast loads)
            const float p4 = pred[4];
            const float px = 1.0f / (1.0f + __expf(-pred[0]));
            const float py = 1.0f / (1.0f + __expf(-pred[1]));
            const float pw = fminf(__expf(pred[2]), 1000.0f) * aw;
            const float ph = fminf(__expf(pred[3]), 1000.0f) * ah;
            const float tx0 = fx - tbw*0.5f, ty0 = fy - tbh*0.5f;
            const float tx1 = fx + tbw*0.5f, ty1 = fy + tbh*0.5f;
            const float bx0 = px - pw*0.5f, by0 = py - ph*0.5f;
            const float bx1 = px + pw*0.5f, by1 = py + ph*0.5f;
            const float jx0 = fmaxf(bx0, tx0), jy0 = fmaxf(by0, ty0);
            const float jx1 = fminf(bx1, tx1), jy1 = fminf(by1, ty1);
            float inter2 = (jx1-jx0)*(jy1-jy0);
            inter2 = (jx0 < jx1 && jy0 < jy1) ? inter2 : 0.0f;
            const float iou2 = inter2 / (pw*ph + tbw*tbh - inter2);

            // cls term: lanes split the 80 classes (lane, lane+64)
            float v = softplusf(pred[5 + lane]);
            if (lane == cls) v -= pred[5 + cls];
            if (lane < 16) {
                const int c2 = 64 + lane;
                v += softplusf(pred[5 + c2]);
                if (c2 == cls) v -= pred[5 + c2];
            }
            #pragma unroll
            for (int off = 32; off > 0; off >>= 1) v += __shfl_down(v, off, 64);

            // t_obj dedupe: claim iff NO earlier target t' in this batch hits
            // the same (ci,cj) at this (s,a). Lanes 0..31 test t'=b*32+lane.
            bool dup = false;
            if (lane < (t & 31)) {
                const int t2 = (b << 5) + lane;
                const float x2 = targets[t2*5+0];
                const float y2 = targets[t2*5+1];
                const float w2 = targets[t2*5+2];
                const float h2 = targets[t2*5+3];
                int ci2, cj2; float fx2, fy2, tbw2, tbh2;
                const bool hit2 = anchor_hit(x2, y2, w2, h2, st, aw, ah,
                                             ci2, cj2, fx2, fy2, tbw2, tbh2);
                dup = hit2 && (ci2 == ci) && (cj2 == cj);
            }
            const unsigned long long m = __ballot(dup);

            if (lane == 0) {  // LDS atomics only (4 waves/block, cheap)
                atomicAdd(&s_part[1 + s], 1.0f);
                atomicAdd(&s_part[4 + s], 1.0f - iou2);
                atomicAdd(&s_part[7 + s], v);
                if (m == 0ull) atomicAdd(&s_part[0], -p4 * invM);
            }
        }
        __syncthreads();
        if (threadIdx.x < 10)
            ws[blockIdx.x * 10 + threadIdx.x] = s_part[threadIdx.x];
    } else {
        // ---------------- dense obj baseline path ----------------
        const int bi  = blockIdx.x - TBLOCKS;
        const int idx = bi * 256 + threadIdx.x;
        const float* inf; int local; float w;
        if (idx < S0)           { inf = inf0; local = idx;             w = 1.0f/(float)S0; }
        else if (idx < S0 + S1) { inf = inf1; local = idx - S0;        w = 1.0f/(float)S1; }
        else                    { inf = inf2; local = idx - (S0 + S1); w = 1.0f/(float)S2; }
        float v = softplusf(inf[(long)local * 85 + 4]) * w;
        #pragma unroll
        for (int off = 32; off > 0; off >>= 1) v += __shfl_down(v, off, 64);
        __shared__ float wsum[4];
        const int lane = threadIdx.x & 63, wid = threadIdx.x >> 6;
        if (lane == 0) wsum[wid] = v;
        __syncthreads();
        if (threadIdx.x == 0)
            ws[WS_OBJ + bi] = wsum[0] + wsum[1] + wsum[2] + wsum[3];
    }
}

// K2: reduce all block partials and emit the scalar loss.
__global__ __launch_bounds__(256) void yolo_finalize_kernel(
    const float* __restrict__ ws, float* __restrict__ out)
{
    float acc[10];
    #pragma unroll
    for (int c = 0; c < 10; ++c) acc[c] = 0.0f;
    for (int r = threadIdx.x; r < TBLOCKS; r += 256) {
        #pragma unroll
        for (int c = 0; c < 10; ++c) acc[c] += ws[r * 10 + c];
    }
    float obj = 0.0f;
    for (int i = threadIdx.x; i < OBLOCKS; i += 256) obj += ws[WS_OBJ + i];
    acc[0] += obj;

    #pragma unroll
    for (int c = 0; c < 10; ++c) {
        float v = acc[c];
        #pragma unroll
        for (int off = 32; off > 0; off >>= 1) v += __shfl_down(v, off, 64);
        acc[c] = v;
    }
    __shared__ float red[4][10];
    const int lane = threadIdx.x & 63, wid = threadIdx.x >> 6;
    if (lane == 0) {
        #pragma unroll
        for (int c = 0; c < 10; ++c) red[wid][c] = acc[c];
    }
    __syncthreads();
    if (threadIdx.x == 0) {
        float tt[10];
        #pragma unroll
        for (int c = 0; c < 10; ++c)
            tt[c] = red[0][c] + red[1][c] + red[2][c] + red[3][c];
        float box = 0.0f, cls = 0.0f;
        #pragma unroll
        for (int s = 0; s < 3; ++s) {
            const float cnt = fmaxf(tt[1 + s], 1.0f);
            box += tt[4 + s] / cnt;
            cls += tt[7 + s] / (cnt * 80.0f);
        }
        out[0] = 3.54f * box + 64.3f * tt[0] + 37.4f * cls;
    }
}

extern "C" void kernel_launch(void* const* d_in, const int* in_sizes, int n_in,
                              void* d_out, int out_size, void* d_ws, size_t ws_size,
                              hipStream_t stream) {
    const float* inf0    = (const float*)d_in[0];
    const float* inf1    = (const float*)d_in[1];
    const float* inf2    = (const float*)d_in[2];
    const float* anchors = (const float*)d_in[3];
    const float* strides = (const float*)d_in[4];
    const float* targets = (const float*)d_in[5];
    float* ws  = (float*)d_ws;
    float* out = (float*)d_out;

    yolo_main_kernel<<<TBLOCKS + OBLOCKS, 256, 0, stream>>>(
        inf0, inf1, inf2, anchors, strides, targets, ws);
    yolo_finalize_kernel<<<1, 256, 0, stream>>>(ws, out);
}

// Round 4
// 113.434 us; speedup vs baseline: 3.6922x; 1.0037x over previous
//
#include <hip/hip_runtime.h>

// Shapes: B=16, N=32 (512 targets), NS=3 scales, NA=3 anchors, NC=80.
// Grids 64/32/16. Cells per scale = 16*3*g*g.
constexpr int S0 = 16 * 3 * 64 * 64;  // 196608
constexpr int S1 = 16 * 3 * 32 * 32;  // 49152
constexpr int S2 = 16 * 3 * 16 * 16;  // 12288
constexpr int TOT = S0 + S1 + S2;     // 258048

// Dense obj path: 4 cells/thread, 1024 cells/block -> scale-pure blocks
// (192 for s0, 48 for s1, 12 for s2).
constexpr int DBLOCKS = TOT / 1024;   // 252
constexpr int DB0 = S0 / 1024;        // 192
constexpr int DB1 = DB0 + S1 / 1024;  // 240

constexpr int TWAVES  = 512 * 9;      // one wave per (t,s,a)
constexpr int TBLOCKS = TWAVES / 4;   // 1152 blocks of 256 (4 waves)

// ws layout (floats): [0, TBLOCKS*10)           target-block partial rows
//                     [WS_OBJ, WS_OBJ+DBLOCKS)  dense obj partials
constexpr int WS_OBJ = TBLOCKS * 10;  // 11520

__device__ __forceinline__ float softplusf(float x) {
    return fmaxf(x, 0.0f) + __logf(1.0f + __expf(-fabsf(x)));
}

// Anchor-IoU hit test. Single definition so the wave's own test and the
// earlier-target dedupe test are bit-exact identical.
__device__ __forceinline__ bool anchor_hit(
    float x, float y, float w, float h, float st, float aw, float ah,
    int& ci, int& cj, float& fx, float& fy, float& tbw, float& tbh)
{
    const float tbx = x / st, tby = y / st;
    tbw = w / st; tbh = h / st;
    const float cif = floorf(tbx), cjf = floorf(tby);
    ci = (int)cif; cj = (int)cjf;
    fx = tbx - cif; fy = tby - cjf;
    const float tx0 = fx - tbw*0.5f, ty0 = fy - tbh*0.5f;
    const float tx1 = fx + tbw*0.5f, ty1 = fy + tbh*0.5f;
    const float ax0 = 0.5f - aw*0.5f, ay0 = 0.5f - ah*0.5f;
    const float ax1 = 0.5f + aw*0.5f, ay1 = 0.5f + ah*0.5f;
    const float ix0 = fmaxf(tx0, ax0), iy0 = fmaxf(ty0, ay0);
    const float ix1 = fminf(tx1, ax1), iy1 = fminf(ty1, ay1);
    float inter = (ix1-ix0)*(iy1-iy0);
    inter = (ix0 < ix1 && iy0 < iy1) ? inter : 0.0f;
    const float iou = inter / (tbw*tbh + aw*ah - inter);
    return iou > 0.5f;
}

// K1 (fused): blocks [0, DBLOCKS) -> dense obj baseline, 4 cells/thread;
// blocks [DBLOCKS, DBLOCKS+TBLOCKS) -> per-target work, one WAVE per (t,s,a).
// No global atomics: every block writes its partial to a private ws slot.
__global__ __launch_bounds__(256) void yolo_main_kernel(
    const float* __restrict__ inf0, const float* __restrict__ inf1,
    const float* __restrict__ inf2, const float* __restrict__ anchors,
    const float* __restrict__ strides, const float* __restrict__ targets,
    float* __restrict__ ws)
{
    if (blockIdx.x < DBLOCKS) {
        // ---------------- dense obj baseline: 1024 scale-pure cells --------
        const int bi = blockIdx.x;
        const float* inf; int base; float w;
        if (bi < DB0)      { inf = inf0; base = bi * 1024;          w = 1.0f/(float)S0; }
        else if (bi < DB1) { inf = inf1; base = (bi - DB0) * 1024;  w = 1.0f/(float)S1; }
        else               { inf = inf2; base = (bi - DB1) * 1024;  w = 1.0f/(float)S2; }
        const int l0 = base + threadIdx.x;
        // 4 independent loads in flight per thread (MLP).
        const float a0 = inf[(long)(l0      ) * 85 + 4];
        const float a1 = inf[(long)(l0 + 256) * 85 + 4];
        const float a2 = inf[(long)(l0 + 512) * 85 + 4];
        const float a3 = inf[(long)(l0 + 768) * 85 + 4];
        float v = softplusf(a0) + softplusf(a1) + softplusf(a2) + softplusf(a3);
        #pragma unroll
        for (int off = 32; off > 0; off >>= 1) v += __shfl_down(v, off, 64);
        __shared__ float wsum[4];
        const int lane = threadIdx.x & 63, wid = threadIdx.x >> 6;
        if (lane == 0) wsum[wid] = v;
        __syncthreads();
        if (threadIdx.x == 0)
            ws[WS_OBJ + bi] = (wsum[0] + wsum[1] + wsum[2] + wsum[3]) * w;
    } else {
        // ---------------- target path: one wave per (t,s,a) ----------------
        __shared__ float s_part[10];
        if (threadIdx.x < 10) s_part[threadIdx.x] = 0.0f;
        __syncthreads();

        const int tb   = blockIdx.x - DBLOCKS;
        const int wave = tb * 4 + (threadIdx.x >> 6);
        const int lane = threadIdx.x & 63;
        const int t  = wave / 9;
        const int sa = wave - 9 * t;
        const int s  = sa / 3;
        const int a  = sa - 3 * s;
        const int b  = t >> 5;

        const float x = targets[t*5+0];
        const float y = targets[t*5+1];
        const float w = targets[t*5+2];
        const float h = targets[t*5+3];
        const int cls = (int)targets[t*5+4];

        const float st = strides[s];
        const float aw = anchors[(s*3+a)*2+0] / st;
        const float ah = anchors[(s*3+a)*2+1] / st;

        int ci, cj; float fx, fy, tbw, tbh;
        const bool hit = anchor_hit(x, y, w, h, st, aw, ah,
                                    ci, cj, fx, fy, tbw, tbh);
        if (hit) {  // wave-uniform
            const int g = (s == 0) ? 64 : (s == 1) ? 32 : 16;
            const float* inf = (s == 0) ? inf0 : (s == 1) ? inf1 : inf2;
            const float invM = (s == 0) ? 1.0f/(float)S0
                             : (s == 1) ? 1.0f/(float)S1 : 1.0f/(float)S2;

            const int cellflat = ((b*3 + a)*g + cj)*g + ci;
            const float* pred = inf + (long)cellflat * 85;

            // box term (redundant across lanes; broadcast loads)
            const float p4 = pred[4];
            const float px = 1.0f / (1.0f + __expf(-pred[0]));
            const float py = 1.0f / (1.0f + __expf(-pred[1]));
            const float pw = fminf(__expf(pred[2]), 1000.0f) * aw;
            const float ph = fminf(__expf(pred[3]), 1000.0f) * ah;
            const float tx0 = fx - tbw*0.5f, ty0 = fy - tbh*0.5f;
            const float tx1 = fx + tbw*0.5f, ty1 = fy + tbh*0.5f;
            const float bx0 = px - pw*0.5f, by0 = py - ph*0.5f;
            const float bx1 = px + pw*0.5f, by1 = py + ph*0.5f;
            const float jx0 = fmaxf(bx0, tx0), jy0 = fmaxf(by0, ty0);
            const float jx1 = fminf(bx1, tx1), jy1 = fminf(by1, ty1);
            float inter2 = (jx1-jx0)*(jy1-jy0);
            inter2 = (jx0 < jx1 && jy0 < jy1) ? inter2 : 0.0f;
            const float iou2 = inter2 / (pw*ph + tbw*tbh - inter2);

            // cls term: lanes split the 80 classes (lane, lane+64)
            float v = softplusf(pred[5 + lane]);
            if (lane == cls) v -= pred[5 + cls];
            if (lane < 16) {
                const int c2 = 64 + lane;
                v += softplusf(pred[5 + c2]);
                if (c2 == cls) v -= pred[5 + c2];
            }
            #pragma unroll
            for (int off = 32; off > 0; off >>= 1) v += __shfl_down(v, off, 64);

            // t_obj dedupe: claim iff NO earlier target t' in this batch hits
            // the same (ci,cj) at this (s,a). Lanes 0..31 test t'=b*32+lane.
            bool dup = false;
            if (lane < (t & 31)) {
                const int t2 = (b << 5) + lane;
                const float x2 = targets[t2*5+0];
                const float y2 = targets[t2*5+1];
                const float w2 = targets[t2*5+2];
                const float h2 = targets[t2*5+3];
                int ci2, cj2; float fx2, fy2, tbw2, tbh2;
                const bool hit2 = anchor_hit(x2, y2, w2, h2, st, aw, ah,
                                             ci2, cj2, fx2, fy2, tbw2, tbh2);
                dup = hit2 && (ci2 == ci) && (cj2 == cj);
            }
            const unsigned long long m = __ballot(dup);

            if (lane == 0) {  // LDS atomics only (4 waves/block, cheap)
                atomicAdd(&s_part[1 + s], 1.0f);
                atomicAdd(&s_part[4 + s], 1.0f - iou2);
                atomicAdd(&s_part[7 + s], v);
                if (m == 0ull) atomicAdd(&s_part[0], -p4 * invM);
            }
        }
        __syncthreads();
        if (threadIdx.x < 10)
            ws[tb * 10 + threadIdx.x] = s_part[threadIdx.x];
    }
}

// K2: reduce all block partials and emit the scalar loss.
__global__ __launch_bounds__(256) void yolo_finalize_kernel(
    const float* __restrict__ ws, float* __restrict__ out)
{
    float acc[10];
    #pragma unroll
    for (int c = 0; c < 10; ++c) acc[c] = 0.0f;
    for (int r = threadIdx.x; r < TBLOCKS; r += 256) {
        #pragma unroll
        for (int c = 0; c < 10; ++c) acc[c] += ws[r * 10 + c];
    }
    float obj = 0.0f;
    for (int i = threadIdx.x; i < DBLOCKS; i += 256) obj += ws[WS_OBJ + i];
    acc[0] += obj;

    #pragma unroll
    for (int c = 0; c < 10; ++c) {
        float v = acc[c];
        #pragma unroll
        for (int off = 32; off > 0; off >>= 1) v += __shfl_down(v, off, 64);
        acc[c] = v;
    }
    __shared__ float red[4][10];
    const int lane = threadIdx.x & 63, wid = threadIdx.x >> 6;
    if (lane == 0) {
        #pragma unroll
        for (int c = 0; c < 10; ++c) red[wid][c] = acc[c];
    }
    __syncthreads();
    if (threadIdx.x == 0) {
        float tt[10];
        #pragma unroll
        for (int c = 0; c < 10; ++c)
            tt[c] = red[0][c] + red[1][c] + red[2][c] + red[3][c];
        float box = 0.0f, cls = 0.0f;
        #pragma unroll
        for (int s = 0; s < 3; ++s) {
            const float cnt = fmaxf(tt[1 + s], 1.0f);
            box += tt[4 + s] / cnt;
            cls += tt[7 + s] / (cnt * 80.0f);
        }
        out[0] = 3.54f * box + 64.3f * tt[0] + 37.4f * cls;
    }
}

extern "C" void kernel_launch(void* const* d_in, const int* in_sizes, int n_in,
                              void* d_out, int out_size, void* d_ws, size_t ws_size,
                              hipStream_t stream) {
    const float* inf0    = (const float*)d_in[0];
    const float* inf1    = (const float*)d_in[1];
    const float* inf2    = (const float*)d_in[2];
    const float* anchors = (const float*)d_in[3];
    const float* strides = (const float*)d_in[4];
    const float* targets = (const float*)d_in[5];
    float* ws  = (float*)d_ws;
    float* out = (float*)d_out;

    yolo_main_kernel<<<DBLOCKS + TBLOCKS, 256, 0, stream>>>(
        inf0, inf1, inf2, anchors, strides, targets, ws);
    yolo_finalize_kernel<<<1, 256, 0, stream>>>(ws, out);
}

// Round 5
// 112.116 us; speedup vs baseline: 3.7356x; 1.0118x over previous
//
#include <hip/hip_runtime.h>

// Shapes: B=16, N=32 (512 targets), NS=3 scales, NA=3 anchors, NC=80.
// Grids 64/32/16. Cells per scale = 16*3*g*g.
constexpr int S0 = 16 * 3 * 64 * 64;  // 196608
constexpr int S1 = 16 * 3 * 32 * 32;  // 49152
constexpr int S2 = 16 * 3 * 16 * 16;  // 12288
constexpr int TOT = S0 + S1 + S2;     // 258048

// Dense obj path: 8 cells/thread, 2048 cells/block -> scale-pure blocks.
constexpr int DBLOCKS = TOT / 2048;   // 126
constexpr int DB0 = S0 / 2048;        // 96
constexpr int DB1 = DB0 + S1 / 2048;  // 120

// Target path: one WAVE per target, 4 waves/block -> 128 blocks.
constexpr int TBLOCKS = 512 / 4;      // 128

// ws layout (floats): [0, TBLOCKS*10)           target-block partial rows
//                     [WS_OBJ, WS_OBJ+DBLOCKS)  dense obj partials
constexpr int WS_OBJ = TBLOCKS * 10;  // 1280

__device__ __forceinline__ float softplusf(float x) {
    return fmaxf(x, 0.0f) + __logf(1.0f + __expf(-fabsf(x)));
}

// Anchor-IoU hit test. Single definition so the wave's own test and the
// earlier-target dedupe test are bit-exact identical.
__device__ __forceinline__ bool anchor_hit(
    float x, float y, float w, float h, float st, float aw, float ah,
    int& ci, int& cj, float& fx, float& fy, float& tbw, float& tbh)
{
    const float tbx = x / st, tby = y / st;
    tbw = w / st; tbh = h / st;
    const float cif = floorf(tbx), cjf = floorf(tby);
    ci = (int)cif; cj = (int)cjf;
    fx = tbx - cif; fy = tby - cjf;
    const float tx0 = fx - tbw*0.5f, ty0 = fy - tbh*0.5f;
    const float tx1 = fx + tbw*0.5f, ty1 = fy + tbh*0.5f;
    const float ax0 = 0.5f - aw*0.5f, ay0 = 0.5f - ah*0.5f;
    const float ax1 = 0.5f + aw*0.5f, ay1 = 0.5f + ah*0.5f;
    const float ix0 = fmaxf(tx0, ax0), iy0 = fmaxf(ty0, ay0);
    const float ix1 = fminf(tx1, ax1), iy1 = fminf(ty1, ay1);
    float inter = (ix1-ix0)*(iy1-iy0);
    inter = (ix0 < ix1 && iy0 < iy1) ? inter : 0.0f;
    const float iou = inter / (tbw*tbh + aw*ah - inter);
    return iou > 0.5f;
}

// K1 (fused, 254 blocks total):
//   blocks [0, DBLOCKS)              dense obj baseline, 2048 cells/block
//   blocks [DBLOCKS, DBLOCKS+128)    one wave per target, 9 (s,a) unrolled
// No global atomics; each block writes partials to a private ws slot.
__global__ __launch_bounds__(256) void yolo_main_kernel(
    const float* __restrict__ inf0, const float* __restrict__ inf1,
    const float* __restrict__ inf2, const float* __restrict__ anchors,
    const float* __restrict__ strides, const float* __restrict__ targets,
    float* __restrict__ ws)
{
    if (blockIdx.x < DBLOCKS) {
        // ---------------- dense obj baseline: 2048 scale-pure cells --------
        const int bi = blockIdx.x;
        const float* inf; int base; float w;
        if (bi < DB0)      { inf = inf0; base = bi * 2048;          w = 1.0f/(float)S0; }
        else if (bi < DB1) { inf = inf1; base = (bi - DB0) * 2048;  w = 1.0f/(float)S1; }
        else               { inf = inf2; base = (bi - DB1) * 2048;  w = 1.0f/(float)S2; }
        const int l0 = base + threadIdx.x;
        float v = 0.0f;
        #pragma unroll
        for (int k = 0; k < 8; ++k)
            v += softplusf(inf[(long)(l0 + k * 256) * 85 + 4]);
        #pragma unroll
        for (int off = 32; off > 0; off >>= 1) v += __shfl_down(v, off, 64);
        __shared__ float wsum[4];
        const int lane = threadIdx.x & 63, wid = threadIdx.x >> 6;
        if (lane == 0) wsum[wid] = v;
        __syncthreads();
        if (threadIdx.x == 0)
            ws[WS_OBJ + bi] = (wsum[0] + wsum[1] + wsum[2] + wsum[3]) * w;
    } else {
        // ---------------- target path: one wave per target -----------------
        const int tb   = blockIdx.x - DBLOCKS;
        const int wid  = threadIdx.x >> 6;
        const int lane = threadIdx.x & 63;
        const int t    = tb * 4 + wid;   // 0..511
        const int b    = t >> 5;

        const float x = targets[t*5+0];
        const float y = targets[t*5+1];
        const float w = targets[t*5+2];
        const float h = targets[t*5+3];
        const int cls = (int)targets[t*5+4];

        float acc[10];
        #pragma unroll
        for (int c = 0; c < 10; ++c) acc[c] = 0.0f;

        #pragma unroll
        for (int sa = 0; sa < 9; ++sa) {
            const int s = sa / 3;
            const int a = sa - 3 * s;
            const float st = strides[s];
            const float aw = anchors[(s*3+a)*2+0] / st;
            const float ah = anchors[(s*3+a)*2+1] / st;

            int ci, cj; float fx, fy, tbw, tbh;
            const bool hit = anchor_hit(x, y, w, h, st, aw, ah,
                                        ci, cj, fx, fy, tbw, tbh);
            if (hit) {  // wave-uniform
                const int g = (s == 0) ? 64 : (s == 1) ? 32 : 16;
                const float* inf = (s == 0) ? inf0 : (s == 1) ? inf1 : inf2;
                const float invM = (s == 0) ? 1.0f/(float)S0
                                 : (s == 1) ? 1.0f/(float)S1 : 1.0f/(float)S2;

                const int cellflat = ((b*3 + a)*g + cj)*g + ci;
                const float* pred = inf + (long)cellflat * 85;

                // box term (redundant across lanes; broadcast loads)
                const float p4 = pred[4];
                const float px = 1.0f / (1.0f + __expf(-pred[0]));
                const float py = 1.0f / (1.0f + __expf(-pred[1]));
                const float pw = fminf(__expf(pred[2]), 1000.0f) * aw;
                const float ph = fminf(__expf(pred[3]), 1000.0f) * ah;
                const float tx0 = fx - tbw*0.5f, ty0 = fy - tbh*0.5f;
                const float tx1 = fx + tbw*0.5f, ty1 = fy + tbh*0.5f;
                const float bx0 = px - pw*0.5f, by0 = py - ph*0.5f;
                const float bx1 = px + pw*0.5f, by1 = py + ph*0.5f;
                const float jx0 = fmaxf(bx0, tx0), jy0 = fmaxf(by0, ty0);
                const float jx1 = fminf(bx1, tx1), jy1 = fminf(by1, ty1);
                float inter2 = (jx1-jx0)*(jy1-jy0);
                inter2 = (jx0 < jx1 && jy0 < jy1) ? inter2 : 0.0f;
                const float iou2 = inter2 / (pw*ph + tbw*tbh - inter2);

                // cls term: lanes split the 80 classes (lane, lane+64)
                float v = softplusf(pred[5 + lane]);
                if (lane == cls) v -= pred[5 + cls];
                if (lane < 16) {
                    const int c2 = 64 + lane;
                    v += softplusf(pred[5 + c2]);
                    if (c2 == cls) v -= pred[5 + c2];
                }
                #pragma unroll
                for (int off = 32; off > 0; off >>= 1)
                    v += __shfl_down(v, off, 64);

                // t_obj dedupe: claim iff NO earlier target t'<t in this batch
                // hits the same (ci,cj) at this (s,a). Lanes 0..31 test
                // t'=b*32+lane with the bit-exact same anchor_hit.
                bool dup = false;
                if (lane < (t & 31)) {
                    const int t2 = (b << 5) + lane;
                    const float x2 = targets[t2*5+0];
                    const float y2 = targets[t2*5+1];
                    const float w2 = targets[t2*5+2];
                    const float h2 = targets[t2*5+3];
                    int ci2, cj2; float fx2, fy2, tbw2, tbh2;
                    const bool hit2 = anchor_hit(x2, y2, w2, h2, st, aw, ah,
                                                 ci2, cj2, fx2, fy2, tbw2, tbh2);
                    dup = hit2 && (ci2 == ci) && (cj2 == cj);
                }
                const unsigned long long m = __ballot(dup);

                acc[1 + s] += 1.0f;
                acc[4 + s] += 1.0f - iou2;
                acc[7 + s] += v;           // lane 0 holds the reduced value
                if (m == 0ull) acc[0] += -p4 * invM;
            }
        }

        // combine the 4 waves' rows (lane 0 of each holds valid acc)
        __shared__ float rows[4][10];
        if (lane == 0) {
            #pragma unroll
            for (int c = 0; c < 10; ++c) rows[wid][c] = acc[c];
        }
        __syncthreads();
        if (threadIdx.x < 10)
            ws[tb * 10 + threadIdx.x] = rows[0][threadIdx.x] +
                rows[1][threadIdx.x] + rows[2][threadIdx.x] +
                rows[3][threadIdx.x];
    }
}

// K2: reduce all block partials and emit the scalar loss.
__global__ __launch_bounds__(256) void yolo_finalize_kernel(
    const float* __restrict__ ws, float* __restrict__ out)
{
    float acc[10];
    #pragma unroll
    for (int c = 0; c < 10; ++c) acc[c] = 0.0f;
    for (int r = threadIdx.x; r < TBLOCKS; r += 256) {
        #pragma unroll
        for (int c = 0; c < 10; ++c) acc[c] += ws[r * 10 + c];
    }
    float obj = 0.0f;
    for (int i = threadIdx.x; i < DBLOCKS; i += 256) obj += ws[WS_OBJ + i];
    acc[0] += obj;

    #pragma unroll
    for (int c = 0; c < 10; ++c) {
        float v = acc[c];
        #pragma unroll
        for (int off = 32; off > 0; off >>= 1) v += __shfl_down(v, off, 64);
        acc[c] = v;
    }
    __shared__ float red[4][10];
    const int lane = threadIdx.x & 63, wid = threadIdx.x >> 6;
    if (lane == 0) {
        #pragma unroll
        for (int c = 0; c < 10; ++c) red[wid][c] = acc[c];
    }
    __syncthreads();
    if (threadIdx.x == 0) {
        float tt[10];
        #pragma unroll
        for (int c = 0; c < 10; ++c)
            tt[c] = red[0][c] + red[1][c] + red[2][c] + red[3][c];
        float box = 0.0f, cls = 0.0f;
        #pragma unroll
        for (int s = 0; s < 3; ++s) {
            const float cnt = fmaxf(tt[1 + s], 1.0f);
            box += tt[4 + s] / cnt;
            cls += tt[7 + s] / (cnt * 80.0f);
        }
        out[0] = 3.54f * box + 64.3f * tt[0] + 37.4f * cls;
    }
}

extern "C" void kernel_launch(void* const* d_in, const int* in_sizes, int n_in,
                              void* d_out, int out_size, void* d_ws, size_t ws_size,
                              hipStream_t stream) {
    const float* inf0    = (const float*)d_in[0];
    const float* inf1    = (const float*)d_in[1];
    const float* inf2    = (const float*)d_in[2];
    const float* anchors = (const float*)d_in[3];
    const float* strides = (const float*)d_in[4];
    const float* targets = (const float*)d_in[5];
    float* ws  = (float*)d_ws;
    float* out = (float*)d_out;

    yolo_main_kernel<<<DBLOCKS + TBLOCKS, 256, 0, stream>>>(
        inf0, inf1, inf2, anchors, strides, targets, ws);
    yolo_finalize_kernel<<<1, 256, 0, stream>>>(ws, out);
}